// Round 1
// baseline (223.751 us; speedup 1.0000x reference)
//
#include <hip/hip_runtime.h>

// Problem geometry (fixed by the reference): B=8, H=1024, W=1024, periodic.
#define WMASK 1023
#define LOG2W 10
#define HW (1024 * 1024)

#define EPS 1e-6f
#define DT 1e-2f

// Output tile 64x16, 256 threads, each phase-2 thread owns one float4.
#define TX 64
#define TY 16

// dF tile: x in [x0-4, x0+67] -> 18 float4 chunks (72 floats, 69 used),
//          y in [y0-1, y0+16] -> 18 rows.
#define DCH 18          // float4 chunks per dF row
#define DYT 18          // dF rows
#define DST 72          // dF LDS row stride in floats (16B-aligned rows)

typedef float f4 __attribute__((ext_vector_type(4)));

__device__ __forceinline__ float scal(const float* __restrict__ p) {
    return fabsf(p[0]) + 0.001f;
}
__device__ __forceinline__ float logm(float m) {
    // jnp.log(jnp.where(m < eps, eps, m)); hw log err ~1e-5 abs, fine vs 2e-2 thr
    return __logf(m < EPS ? EPS : m);
}
__device__ __forceinline__ float clip01(float v) {
    return fminf(fmaxf(v, 0.0f), 1.0f);
}

__global__ __launch_bounds__(256) void irr_fused(
    const float* __restrict__ cv,
    const float* __restrict__ ci,
    const float* __restrict__ eta,
    const float* __restrict__ p_ev,
    const float* __restrict__ p_ei,
    const float* __restrict__ p_kbt,
    const float* __restrict__ p_kv,
    const float* __restrict__ p_ki,
    const float* __restrict__ p_ke,
    const float* __restrict__ p_dv,
    const float* __restrict__ p_di,
    const float* __restrict__ p_L,
    float* __restrict__ cv_new,
    float* __restrict__ ci_new,
    float* __restrict__ eta_new)
{
    // Only the dF fields live in LDS now (10.4 KB): raw-field 5-pt reads go
    // straight to global (block footprint ~19 KB -> L1/L2 hit; L3 holds the
    // full 100 MB read set, so HBM traffic stays ~1 read per element).
    __shared__ float sdv[DYT][DST];
    __shared__ float sdi[DYT][DST];

    const int tid = threadIdx.x;
    const int x0 = blockIdx.x * TX;
    const int y0 = blockIdx.y * TY;
    const int bbase = blockIdx.z * HW;

    const float energy_v = scal(p_ev);
    const float energy_i = scal(p_ei);
    const float kBT      = scal(p_kbt);
    const float kappa_v  = scal(p_kv);
    const float kappa_i  = scal(p_ki);
    const float kappa_e  = scal(p_ke);
    const float diff_v   = scal(p_dv);
    const float diff_i   = scal(p_di);
    const float L        = scal(p_L);
    const float rv = diff_v / kBT;     // mv = rv * cv
    const float ri = diff_i / kBT;

    // ---- Phase 1: dF_dcv / dF_dci on the 72x18 tile (4 elems/thread-task),
    //      eta_new finished inline for interior chunks. ----
    for (int t = tid; t < DCH * DYT; t += 256) {
        const int ex4 = t % DCH;                       // chunk col
        const int ey  = t / DCH;                       // dF row
        const int gx  = (x0 - 4 + (ex4 << 2)) & WMASK; // 4-aligned, wrap-safe
        const int gxl = (gx - 1) & WMASK;
        const int gxr = (gx + 4) & WMASK;
        const int gy  = (y0 - 1 + ey) & WMASK;
        const int rowC = bbase + (gy << LOG2W);
        const int rowU = bbase + (((gy - 1) & WMASK) << LOG2W);
        const int rowD = bbase + (((gy + 1) & WMASK) << LOG2W);

        const f4    cC = *(const f4*)(cv + rowC + gx);
        const float cL = cv[rowC + gxl];
        const float cR = cv[rowC + gxr];
        const f4    cU = *(const f4*)(cv + rowU + gx);
        const f4    cD = *(const f4*)(cv + rowD + gx);

        const f4    iC = *(const f4*)(ci + rowC + gx);
        const float iL = ci[rowC + gxl];
        const float iR = ci[rowC + gxr];
        const f4    iU = *(const f4*)(ci + rowU + gx);
        const f4    iD = *(const f4*)(ci + rowD + gx);

        const f4    eC = *(const f4*)(eta + rowC + gx);
        const float eL = eta[rowC + gxl];
        const float eR = eta[rowC + gxr];
        const f4    eU = *(const f4*)(eta + rowU + gx);
        const f4    eD = *(const f4*)(eta + rowD + gx);

        f4 dv, di, en;
        #pragma unroll
        for (int j = 0; j < 4; ++j) {
            const float c0 = cC[j];
            const float i0 = iC[j];
            const float e0 = eC[j];
            const float cl = (j == 0) ? cL : cC[j - 1];
            const float cr = (j == 3) ? cR : cC[j + 1];
            const float il = (j == 0) ? iL : iC[j - 1];
            const float ir = (j == 3) ? iR : iC[j + 1];
            const float el = (j == 0) ? eL : eC[j - 1];
            const float er = (j == 3) ? eR : eC[j + 1];

            const float lap_cv  = cl + cr + cU[j] + cD[j] - 4.0f * c0;
            const float lap_ci  = il + ir + iU[j] + iD[j] - 4.0f * i0;
            const float lap_eta = el + er + eU[j] + eD[j] - 4.0f * e0;

            const float h  = (e0 - 1.0f) * (e0 - 1.0f);
            const float jj = e0 * e0;
            const float cs = 1.0f - c0 - i0;
            const float lgv = logm(c0);
            const float lgi = logm(i0);
            const float lgs = logm(cs);

            const float dfs_dcv = energy_v + kBT * (lgv - lgs);
            const float dfs_dci = energy_i + kBT * (lgi - lgs);

            dv[j] = h * dfs_dcv + jj * (2.0f * (c0 - 1.0f)) - kappa_v * lap_cv;
            di[j] = h * dfs_dci + jj * (2.0f * i0)          - kappa_i * lap_ci;

            const float fs = energy_v * c0 + energy_i * i0
                           + kBT * (c0 * lgv + i0 * lgi + cs * lgs);
            const float fv = (c0 - 1.0f) * (c0 - 1.0f) + i0 * i0;
            const float dF_deta = fs * 2.0f * (e0 - 1.0f) + fv * 2.0f * e0
                                - kappa_e * lap_eta;   // N_PARAM == 1.0
            en[j] = clip01(e0 + DT * (-L * dF_deta));
        }

        *(f4*)&sdv[ey][ex4 << 2] = dv;
        *(f4*)&sdi[ey][ex4 << 2] = di;

        // eta_new needs only the 1-ring: interior chunks are final here.
        if (ex4 >= 1 && ex4 <= 16 && ey >= 1 && ey <= 16) {
            const int gidx = bbase + ((y0 - 1 + ey) << LOG2W)
                           + (x0 - 4 + (ex4 << 2));        // no wrap: interior
            __builtin_nontemporal_store(en, (f4*)(eta_new + gidx));
        }
    }
    __syncthreads();

    // ---- Phase 2: second 5-pt stencil over the LDS dF tiles, one float4
    //      per thread, vector LDS reads + float4 nontemporal stores. ----
    {
        const int ox4 = tid & 15;
        const int oy  = tid >> 4;
        const int ex  = (ox4 << 2) + 4;   // dF col of output x
        const int ey  = oy + 1;

        const f4    vC = *(const f4*)&sdv[ey][ex];
        const float vL = sdv[ey][ex - 1];
        const float vR = sdv[ey][ex + 4];
        const f4    vU = *(const f4*)&sdv[ey - 1][ex];
        const f4    vD = *(const f4*)&sdv[ey + 1][ex];

        const f4    wC = *(const f4*)&sdi[ey][ex];
        const float wL = sdi[ey][ex - 1];
        const float wR = sdi[ey][ex + 4];
        const f4    wU = *(const f4*)&sdi[ey - 1][ex];
        const f4    wD = *(const f4*)&sdi[ey + 1][ex];

        const int gx = x0 + (ox4 << 2);
        const int gy = y0 + oy;
        const int gidx = bbase + (gy << LOG2W) + gx;

        const f4 c0 = *(const f4*)(cv + gidx);   // L1/L2 hit (read in phase 1)
        const f4 i0 = *(const f4*)(ci + gidx);

        f4 outv, outi;
        #pragma unroll
        for (int j = 0; j < 4; ++j) {
            const float lv = ((j == 0) ? vL : vC[j - 1])
                           + ((j == 3) ? vR : vC[j + 1])
                           + vU[j] + vD[j] - 4.0f * vC[j];
            const float li = ((j == 0) ? wL : wC[j - 1])
                           + ((j == 3) ? wR : wC[j + 1])
                           + wU[j] + wD[j] - 4.0f * wC[j];
            outv[j] = clip01(c0[j] + DT * ((rv * c0[j]) * lv));
            outi[j] = clip01(i0[j] + DT * ((ri * i0[j]) * li));
        }
        __builtin_nontemporal_store(outv, (f4*)(cv_new + gidx));
        __builtin_nontemporal_store(outi, (f4*)(ci_new + gidx));
    }
}

extern "C" void kernel_launch(void* const* d_in, const int* in_sizes, int n_in,
                              void* d_out, int out_size, void* d_ws, size_t ws_size,
                              hipStream_t stream) {
    // Input order: cv, ci, eta, energy_v0, energy_i0, kBT0, kappa_v0, kappa_i0,
    //              kappa_eta0, diff_v0, diff_i0, L0  — all float32 per reference.
    const float* cv  = (const float*)d_in[0];
    const float* ci  = (const float*)d_in[1];
    const float* eta = (const float*)d_in[2];
    const float* p_ev  = (const float*)d_in[3];
    const float* p_ei  = (const float*)d_in[4];
    const float* p_kbt = (const float*)d_in[5];
    const float* p_kv  = (const float*)d_in[6];
    const float* p_ki  = (const float*)d_in[7];
    const float* p_ke  = (const float*)d_in[8];
    const float* p_dv  = (const float*)d_in[9];
    const float* p_di  = (const float*)d_in[10];
    const float* p_L   = (const float*)d_in[11];

    const int N = in_sizes[0];  // 8*1024*1024 elements

    float* out     = (float*)d_out;
    float* cv_new  = out;
    float* ci_new  = out + N;
    float* eta_new = out + 2 * N;

    const dim3 block(256);
    const dim3 grid(1024 / TX, 1024 / TY, N / HW);  // (16, 64, 8)

    irr_fused<<<grid, block, 0, stream>>>(cv, ci, eta, p_ev, p_ei, p_kbt,
                                          p_kv, p_ki, p_ke, p_dv, p_di, p_L,
                                          cv_new, ci_new, eta_new);
}

// Round 2
// 215.205 us; speedup vs baseline: 1.0397x; 1.0397x over previous
//
#include <hip/hip_runtime.h>

// Problem geometry (fixed by the reference): B=8, H=1024, W=1024, periodic.
#define WMASK 1023
#define LOG2W 10
#define HW (1024 * 1024)

#define EPS 1e-6f
#define DT 1e-2f

// Output tile 64x16, 256 threads.
#define TX 64
#define TY 16

// Raw fields staged with halo (x: x0-8 .. x0+75 = 21 float4 chunks, y: y0-2..y0+17).
#define RCH 21          // raw float4 chunks per row
#define RYT 20          // raw rows
#define RST 84          // raw LDS row stride in floats (odd multiple of 4: bank spread)
#define FPAD 448        // per-field task padding (multiple of 64 -> wave-uniform field)

// dF tile: x in [x0-4, x0+67] -> 18 float4 chunks, y in [y0-1, y0+16] -> 18 rows.
#define DCH 18
#define DYT 18
#define DST 76          // dF LDS row stride in floats (odd multiple of 4)

typedef float f4 __attribute__((ext_vector_type(4)));

__device__ __forceinline__ float scal(const float* __restrict__ p) {
    return fabsf(p[0]) + 0.001f;
}
__device__ __forceinline__ float logm(float m) {
    // jnp.log(jnp.where(m < eps, eps, m)); hw log err ~1e-5 abs, fine vs 2e-2 thr
    return __logf(m < EPS ? EPS : m);
}
__device__ __forceinline__ float clip01(float v) {
    return fminf(fmaxf(v, 0.0f), 1.0f);
}

__global__ __launch_bounds__(256) void irr_fused(
    const float* __restrict__ cv,
    const float* __restrict__ ci,
    const float* __restrict__ eta,
    const float* __restrict__ p_ev,
    const float* __restrict__ p_ei,
    const float* __restrict__ p_kbt,
    const float* __restrict__ p_kv,
    const float* __restrict__ p_ki,
    const float* __restrict__ p_ke,
    const float* __restrict__ p_dv,
    const float* __restrict__ p_di,
    const float* __restrict__ p_L,
    float* __restrict__ cv_new,
    float* __restrict__ ci_new,
    float* __restrict__ eta_new)
{
    __shared__ float scv[RYT][RST];
    __shared__ float sci[RYT][RST];
    __shared__ float seta[RYT][RST];
    __shared__ float sdv[DYT][DST];
    __shared__ float sdi[DYT][DST];

    const int tid = threadIdx.x;
    const int x0 = blockIdx.x * TX;
    const int y0 = blockIdx.y * TY;
    const int bbase = blockIdx.z * HW;

    const float energy_v = scal(p_ev);
    const float energy_i = scal(p_ei);
    const float kBT      = scal(p_kbt);
    const float kappa_v  = scal(p_kv);
    const float kappa_i  = scal(p_ki);
    const float kappa_e  = scal(p_ke);
    const float diff_v   = scal(p_dv);
    const float diff_i   = scal(p_di);
    const float L        = scal(p_L);
    const float rv = diff_v / kBT;     // mv = rv * cv
    const float ri = diff_i / kBT;

    // ---- Stage raw fields into LDS with float4 coalesced loads ----
    // 21 chunks x 20 rows = 420 chunks per field; pad per-field index space to
    // 448 (multiple of 64) so the field pointer is wave-uniform.
    for (int t = tid; t < 3 * FPAD; t += 256) {
        const int f = t / FPAD;
        const int r = t - f * FPAD;
        if (r < RCH * RYT) {
            const int cx = r % RCH;
            const int cy = r / RCH;
            const int gx = (x0 - 8 + (cx << 2)) & WMASK;   // 4-aligned, no row-cross
            const int gy = (y0 - 2 + cy) & WMASK;
            const float* __restrict__ src = (f == 0) ? cv : (f == 1) ? ci : eta;
            const f4 v = *(const f4*)(src + bbase + (gy << LOG2W) + gx);
            float* dst = (f == 0) ? &scv[cy][cx << 2]
                       : (f == 1) ? &sci[cy][cx << 2]
                                  : &seta[cy][cx << 2];
            *(f4*)dst = v;
        }
    }
    __syncthreads();

    // ---- Phase 1: dF fields on the 72x18 extended tile, 4 elems per task,
    //      vector LDS reads; eta_new finished inline for interior chunks. ----
    for (int t = tid; t < DCH * DYT; t += 256) {
        const int k  = t % DCH;          // dF chunk col; global x = x0-4+4k
        const int ey = t / DCH;          // dF row; global y = y0-1+ey
        const int rx = (k << 2) + 4;     // raw LDS float index of chunk base
        const int ry = ey + 1;

        const f4    cC = *(const f4*)&scv[ry][rx];
        const float cL = scv[ry][rx - 1];
        const float cR = scv[ry][rx + 4];
        const f4    cU = *(const f4*)&scv[ry - 1][rx];
        const f4    cD = *(const f4*)&scv[ry + 1][rx];

        const f4    iC = *(const f4*)&sci[ry][rx];
        const float iL = sci[ry][rx - 1];
        const float iR = sci[ry][rx + 4];
        const f4    iU = *(const f4*)&sci[ry - 1][rx];
        const f4    iD = *(const f4*)&sci[ry + 1][rx];

        const f4    eC = *(const f4*)&seta[ry][rx];
        const float eL = seta[ry][rx - 1];
        const float eR = seta[ry][rx + 4];
        const f4    eU = *(const f4*)&seta[ry - 1][rx];
        const f4    eD = *(const f4*)&seta[ry + 1][rx];

        f4 dv, di, en;
        #pragma unroll
        for (int j = 0; j < 4; ++j) {
            const float c0 = cC[j];
            const float i0 = iC[j];
            const float e0 = eC[j];
            const float cl = (j == 0) ? cL : cC[j - 1];
            const float cr = (j == 3) ? cR : cC[j + 1];
            const float il = (j == 0) ? iL : iC[j - 1];
            const float ir = (j == 3) ? iR : iC[j + 1];
            const float el = (j == 0) ? eL : eC[j - 1];
            const float er = (j == 3) ? eR : eC[j + 1];

            const float lap_cv  = cl + cr + cU[j] + cD[j] - 4.0f * c0;
            const float lap_ci  = il + ir + iU[j] + iD[j] - 4.0f * i0;
            const float lap_eta = el + er + eU[j] + eD[j] - 4.0f * e0;

            const float h  = (e0 - 1.0f) * (e0 - 1.0f);
            const float jj = e0 * e0;
            const float cs = 1.0f - c0 - i0;
            const float lgv = logm(c0);
            const float lgi = logm(i0);
            const float lgs = logm(cs);

            const float dfs_dcv = energy_v + kBT * (lgv - lgs);
            const float dfs_dci = energy_i + kBT * (lgi - lgs);

            dv[j] = h * dfs_dcv + jj * (2.0f * (c0 - 1.0f)) - kappa_v * lap_cv;
            di[j] = h * dfs_dci + jj * (2.0f * i0)          - kappa_i * lap_ci;

            const float fs = energy_v * c0 + energy_i * i0
                           + kBT * (c0 * lgv + i0 * lgi + cs * lgs);
            const float fv = (c0 - 1.0f) * (c0 - 1.0f) + i0 * i0;
            const float dF_deta = fs * 2.0f * (e0 - 1.0f) + fv * 2.0f * e0
                                - kappa_e * lap_eta;   // N_PARAM == 1.0
            en[j] = clip01(e0 + DT * (-L * dF_deta));
        }

        *(f4*)&sdv[ey][k << 2] = dv;
        *(f4*)&sdi[ey][k << 2] = di;

        // eta_new needs only the 1-ring: interior chunks are final here.
        if (k >= 1 && k <= 16 && ey >= 1 && ey <= 16) {
            const int gidx = bbase + ((y0 - 1 + ey) << LOG2W)
                           + (x0 - 4 + (k << 2));          // no wrap: interior
            __builtin_nontemporal_store(en, (f4*)(eta_new + gidx));
        }
    }
    __syncthreads();

    // ---- Phase 2: second 5-pt stencil over the LDS dF tiles, one float4
    //      per thread, vector LDS reads + float4 nontemporal stores. ----
    {
        const int ox4 = tid & 15;
        const int oy  = tid >> 4;
        const int ex  = (ox4 << 2) + 4;   // dF float index of output x
        const int ey  = oy + 1;

        const f4    vC = *(const f4*)&sdv[ey][ex];
        const float vL = sdv[ey][ex - 1];
        const float vR = sdv[ey][ex + 4];
        const f4    vU = *(const f4*)&sdv[ey - 1][ex];
        const f4    vD = *(const f4*)&sdv[ey + 1][ex];

        const f4    wC = *(const f4*)&sdi[ey][ex];
        const float wL = sdi[ey][ex - 1];
        const float wR = sdi[ey][ex + 4];
        const f4    wU = *(const f4*)&sdi[ey - 1][ex];
        const f4    wD = *(const f4*)&sdi[ey + 1][ex];

        // centers from the raw LDS tile (still resident)
        const f4 c0 = *(const f4*)&scv[oy + 2][(ox4 << 2) + 8];
        const f4 i0 = *(const f4*)&sci[oy + 2][(ox4 << 2) + 8];

        const int gidx = bbase + ((y0 + oy) << LOG2W) + (x0 + (ox4 << 2));

        f4 outv, outi;
        #pragma unroll
        for (int j = 0; j < 4; ++j) {
            const float lv = ((j == 0) ? vL : vC[j - 1])
                           + ((j == 3) ? vR : vC[j + 1])
                           + vU[j] + vD[j] - 4.0f * vC[j];
            const float li = ((j == 0) ? wL : wC[j - 1])
                           + ((j == 3) ? wR : wC[j + 1])
                           + wU[j] + wD[j] - 4.0f * wC[j];
            outv[j] = clip01(c0[j] + DT * ((rv * c0[j]) * lv));
            outi[j] = clip01(i0[j] + DT * ((ri * i0[j]) * li));
        }
        __builtin_nontemporal_store(outv, (f4*)(cv_new + gidx));
        __builtin_nontemporal_store(outi, (f4*)(ci_new + gidx));
    }
}

extern "C" void kernel_launch(void* const* d_in, const int* in_sizes, int n_in,
                              void* d_out, int out_size, void* d_ws, size_t ws_size,
                              hipStream_t stream) {
    // Input order: cv, ci, eta, energy_v0, energy_i0, kBT0, kappa_v0, kappa_i0,
    //              kappa_eta0, diff_v0, diff_i0, L0  — all float32 per reference.
    const float* cv  = (const float*)d_in[0];
    const float* ci  = (const float*)d_in[1];
    const float* eta = (const float*)d_in[2];
    const float* p_ev  = (const float*)d_in[3];
    const float* p_ei  = (const float*)d_in[4];
    const float* p_kbt = (const float*)d_in[5];
    const float* p_kv  = (const float*)d_in[6];
    const float* p_ki  = (const float*)d_in[7];
    const float* p_ke  = (const float*)d_in[8];
    const float* p_dv  = (const float*)d_in[9];
    const float* p_di  = (const float*)d_in[10];
    const float* p_L   = (const float*)d_in[11];

    const int N = in_sizes[0];  // 8*1024*1024 elements

    float* out     = (float*)d_out;
    float* cv_new  = out;
    float* ci_new  = out + N;
    float* eta_new = out + 2 * N;

    const dim3 block(256);
    const dim3 grid(1024 / TX, 1024 / TY, N / HW);  // (16, 64, 8)

    irr_fused<<<grid, block, 0, stream>>>(cv, ci, eta, p_ev, p_ei, p_kbt,
                                          p_kv, p_ki, p_ke, p_dv, p_di, p_L,
                                          cv_new, ci_new, eta_new);
}

// Round 3
// 212.587 us; speedup vs baseline: 1.0525x; 1.0123x over previous
//
#include <hip/hip_runtime.h>

// Problem geometry (fixed by the reference): B=8, H=1024, W=1024, periodic.
#define WMASK 1023
#define LOG2W 10
#define HW (1024 * 1024)

#define EPS 1e-6f
#define DT 1e-2f

// Output tile 64x16, 256 threads.
#define TX 64
#define TY 16

// Raw cv/ci staged x: [x0-4, x0+67] = 18 chunks (stride 72), y: [y0-2, y0+17] = 20 rows.
// seta needs only y: [y0-1, y0+16] = 18 rows (e0 + interior lap_eta coverage).
// All strides 72 floats = 288 B (bank shift 8/row — the measured-low-conflict
// geometry from round 0). Total LDS = 5760*2 + 5184*3 = 27072 B -> 6 blocks/CU.
#define RCH 18          // float4 chunks per raw row
#define RST 72          // LDS row stride in floats (all tiles)

// dF tile: x in [x0-4, x0+67] -> 18 chunks, y in [y0-1, y0+16] -> 18 rows.
#define DCH 18
#define DYT 18

typedef float f4 __attribute__((ext_vector_type(4)));

__device__ __forceinline__ float scal(const float* __restrict__ p) {
    return fabsf(p[0]) + 0.001f;
}
__device__ __forceinline__ float clip01(float v) {
    return fminf(fmaxf(v, 0.0f), 1.0f);
}
// log2 of clamped arg; caller folds ln2 into the kBT scalar (kl).
__device__ __forceinline__ float lg2m(float m) {
    return __log2f(fmaxf(m, EPS));   // jnp.log(where(m<eps,eps,m)) == ln2*log2(max(m,eps))
}

__global__ __launch_bounds__(256) void irr_fused(
    const float* __restrict__ cv,
    const float* __restrict__ ci,
    const float* __restrict__ eta,
    const float* __restrict__ p_ev,
    const float* __restrict__ p_ei,
    const float* __restrict__ p_kbt,
    const float* __restrict__ p_kv,
    const float* __restrict__ p_ki,
    const float* __restrict__ p_ke,
    const float* __restrict__ p_dv,
    const float* __restrict__ p_di,
    const float* __restrict__ p_L,
    float* __restrict__ cv_new,
    float* __restrict__ ci_new,
    float* __restrict__ eta_new)
{
    __shared__ float scv[20][RST];
    __shared__ float sci[20][RST];
    __shared__ float seta[18][RST];
    __shared__ float sdv[DYT][RST];
    __shared__ float sdi[DYT][RST];

    const int tid = threadIdx.x;
    const int x0 = blockIdx.x * TX;
    const int y0 = blockIdx.y * TY;
    const int bbase = blockIdx.z * HW;

    const float energy_v = scal(p_ev);
    const float energy_i = scal(p_ei);
    const float kBT      = scal(p_kbt);
    const float kappa_v  = scal(p_kv);
    const float kappa_i  = scal(p_ki);
    const float kappa_e  = scal(p_ke);
    const float diff_v   = scal(p_dv);
    const float diff_i   = scal(p_di);
    const float L        = scal(p_L);
    const float rv = diff_v / kBT;             // mv = rv * cv
    const float ri = diff_i / kBT;
    const float kl = kBT * 0.69314718056f;     // kBT * ln2: folds __logf's ln2 mul

    // ---- Stage raw fields into LDS with float4 coalesced loads ----
    // cv: 360 chunks, ci: 360, eta: 324 (18 rows) -> 1044 tasks.
    for (int t = tid; t < 1044; t += 256) {
        const float* __restrict__ src;
        float (*dstA)[RST];
        int r, gy0;
        if (t < 360)      { src = cv;  r = t;       gy0 = y0 - 2; dstA = scv; }
        else if (t < 720) { src = ci;  r = t - 360; gy0 = y0 - 2; dstA = sci; }
        else              { src = eta; r = t - 720; gy0 = y0 - 1; dstA = seta; }
        const int cx = r % RCH;
        const int cy = r / RCH;
        const int gx = (x0 - 4 + (cx << 2)) & WMASK;   // 4-aligned, no row-cross
        const int gy = (gy0 + cy) & WMASK;
        const f4 v = *(const f4*)(src + bbase + (gy << LOG2W) + gx);
        *(f4*)&dstA[cy][cx << 2] = v;
    }
    __syncthreads();

    // ---- Phase 1: dF fields on the 72x18 extended tile, 4 elems per task,
    //      vector LDS reads; eta_new finished inline for interior chunks. ----
    for (int t = tid; t < DCH * DYT; t += 256) {
        const int k  = t % DCH;          // chunk col; global x = x0-4+4k
        const int ey = t / DCH;          // dF row;   global y = y0-1+ey
        const int rx = k << 2;
        const int ry = ey + 1;           // scv/sci row (they start at y0-2)

        const f4 cC = *(const f4*)&scv[ry][rx];
        const f4 cU = *(const f4*)&scv[ry - 1][rx];
        const f4 cD = *(const f4*)&scv[ry + 1][rx];
        const f4 iC = *(const f4*)&sci[ry][rx];
        const f4 iU = *(const f4*)&sci[ry - 1][rx];
        const f4 iD = *(const f4*)&sci[ry + 1][rx];
        const f4 eC = *(const f4*)&seta[ey][rx];
        const int eyU = (ey == 0)  ? 0  : ey - 1;   // clamp: edge rows' lap_eta unused
        const int eyD = (ey == 17) ? 17 : ey + 1;
        const f4 eU = *(const f4*)&seta[eyU][rx];
        const f4 eD = *(const f4*)&seta[eyD][rx];

        float cL, cR, iL, iR, eL, eR;
        if (k == 0) {        // x0-5 not staged: global (L2-hot). eL unused (not interior).
            const int gofs = bbase + (((y0 - 1 + ey) & WMASK) << LOG2W) + ((x0 - 5) & WMASK);
            cL = cv[gofs]; iL = ci[gofs]; eL = 0.0f;
        } else {
            cL = scv[ry][rx - 1]; iL = sci[ry][rx - 1]; eL = seta[ey][rx - 1];
        }
        if (k == DCH - 1) {  // x0+68 not staged: global. eR unused.
            const int gofs = bbase + (((y0 - 1 + ey) & WMASK) << LOG2W) + ((x0 + 68) & WMASK);
            cR = cv[gofs]; iR = ci[gofs]; eR = 0.0f;
        } else {
            cR = scv[ry][rx + 4]; iR = sci[ry][rx + 4]; eR = seta[ey][rx + 4];
        }

        f4 dv, di, en;
        #pragma unroll
        for (int j = 0; j < 4; ++j) {
            const float c0 = cC[j];
            const float i0 = iC[j];
            const float e0 = eC[j];
            const float cl = (j == 0) ? cL : cC[j - 1];
            const float cr = (j == 3) ? cR : cC[j + 1];
            const float il = (j == 0) ? iL : iC[j - 1];
            const float ir = (j == 3) ? iR : iC[j + 1];
            const float el = (j == 0) ? eL : eC[j - 1];
            const float er = (j == 3) ? eR : eC[j + 1];

            const float lap_cv  = cl + cr + cU[j] + cD[j] - 4.0f * c0;
            const float lap_ci  = il + ir + iU[j] + iD[j] - 4.0f * i0;
            const float lap_eta = el + er + eU[j] + eD[j] - 4.0f * e0;

            const float h  = (e0 - 1.0f) * (e0 - 1.0f);
            const float jj = e0 * e0;
            const float cs = 1.0f - c0 - i0;
            const float lgv = lg2m(c0);    // log2; ln2 folded into kl
            const float lgi = lg2m(i0);
            const float lgs = lg2m(cs);

            const float dfs_dcv = energy_v + kl * (lgv - lgs);
            const float dfs_dci = energy_i + kl * (lgi - lgs);

            dv[j] = h * dfs_dcv + jj * (2.0f * (c0 - 1.0f)) - kappa_v * lap_cv;
            di[j] = h * dfs_dci + jj * (2.0f * i0)          - kappa_i * lap_ci;

            const float fs = energy_v * c0 + energy_i * i0
                           + kl * (c0 * lgv + i0 * lgi + cs * lgs);
            const float fv = (c0 - 1.0f) * (c0 - 1.0f) + i0 * i0;
            const float dF_deta = fs * 2.0f * (e0 - 1.0f) + fv * 2.0f * e0
                                - kappa_e * lap_eta;   // N_PARAM == 1.0
            en[j] = clip01(e0 + DT * (-L * dF_deta));
        }

        *(f4*)&sdv[ey][rx] = dv;
        *(f4*)&sdi[ey][rx] = di;

        // eta_new needs only the 1-ring: interior chunks are final here.
        if (k >= 1 && k <= 16 && ey >= 1 && ey <= 16) {
            const int gidx = bbase + ((y0 - 1 + ey) << LOG2W)
                           + (x0 - 4 + (k << 2));          // no wrap: interior
            __builtin_nontemporal_store(en, (f4*)(eta_new + gidx));
        }
    }
    __syncthreads();

    // ---- Phase 2: second 5-pt stencil over the LDS dF tiles, one float4
    //      per thread, vector LDS reads + float4 nontemporal stores. ----
    {
        const int ox4 = tid & 15;
        const int oy  = tid >> 4;
        const int ex  = (ox4 << 2) + 4;   // dF float col of output x
        const int ey  = oy + 1;

        const f4    vC = *(const f4*)&sdv[ey][ex];
        const float vL = sdv[ey][ex - 1];
        const float vR = sdv[ey][ex + 4];
        const f4    vU = *(const f4*)&sdv[ey - 1][ex];
        const f4    vD = *(const f4*)&sdv[ey + 1][ex];

        const f4    wC = *(const f4*)&sdi[ey][ex];
        const float wL = sdi[ey][ex - 1];
        const float wR = sdi[ey][ex + 4];
        const f4    wU = *(const f4*)&sdi[ey - 1][ex];
        const f4    wD = *(const f4*)&sdi[ey + 1][ex];

        // centers from the raw LDS tile (still resident)
        const f4 c0 = *(const f4*)&scv[oy + 2][ex];
        const f4 i0 = *(const f4*)&sci[oy + 2][ex];

        const int gidx = bbase + ((y0 + oy) << LOG2W) + (x0 + (ox4 << 2));

        f4 outv, outi;
        #pragma unroll
        for (int j = 0; j < 4; ++j) {
            const float lv = ((j == 0) ? vL : vC[j - 1])
                           + ((j == 3) ? vR : vC[j + 1])
                           + vU[j] + vD[j] - 4.0f * vC[j];
            const float li = ((j == 0) ? wL : wC[j - 1])
                           + ((j == 3) ? wR : wC[j + 1])
                           + wU[j] + wD[j] - 4.0f * wC[j];
            outv[j] = clip01(c0[j] + DT * ((rv * c0[j]) * lv));
            outi[j] = clip01(i0[j] + DT * ((ri * i0[j]) * li));
        }
        __builtin_nontemporal_store(outv, (f4*)(cv_new + gidx));
        __builtin_nontemporal_store(outi, (f4*)(ci_new + gidx));
    }
}

extern "C" void kernel_launch(void* const* d_in, const int* in_sizes, int n_in,
                              void* d_out, int out_size, void* d_ws, size_t ws_size,
                              hipStream_t stream) {
    // Input order: cv, ci, eta, energy_v0, energy_i0, kBT0, kappa_v0, kappa_i0,
    //              kappa_eta0, diff_v0, diff_i0, L0  — all float32 per reference.
    const float* cv  = (const float*)d_in[0];
    const float* ci  = (const float*)d_in[1];
    const float* eta = (const float*)d_in[2];
    const float* p_ev  = (const float*)d_in[3];
    const float* p_ei  = (const float*)d_in[4];
    const float* p_kbt = (const float*)d_in[5];
    const float* p_kv  = (const float*)d_in[6];
    const float* p_ki  = (const float*)d_in[7];
    const float* p_ke  = (const float*)d_in[8];
    const float* p_dv  = (const float*)d_in[9];
    const float* p_di  = (const float*)d_in[10];
    const float* p_L   = (const float*)d_in[11];

    const int N = in_sizes[0];  // 8*1024*1024 elements

    float* out     = (float*)d_out;
    float* cv_new  = out;
    float* ci_new  = out + N;
    float* eta_new = out + 2 * N;

    const dim3 block(256);
    const dim3 grid(1024 / TX, 1024 / TY, N / HW);  // (16, 64, 8)

    irr_fused<<<grid, block, 0, stream>>>(cv, ci, eta, p_ev, p_ei, p_kbt,
                                          p_kv, p_ki, p_ke, p_dv, p_di, p_L,
                                          cv_new, ci_new, eta_new);
}

// Round 4
// 212.394 us; speedup vs baseline: 1.0535x; 1.0009x over previous
//
#include <hip/hip_runtime.h>

// Problem geometry (fixed by the reference): B=8, H=1024, W=1024, periodic.
#define WMASK 1023
#define LOG2W 10
#define HW (1024 * 1024)

#define EPS 1e-6f
#define DT 1e-2f

// Output tile 64x16, 256 threads, 1 float4 of output per thread.
#define TX 64
#define TY 16

// Raw tiles: x [x0-4, x0+67] = 18 chunks, stride 72 floats.
// cv/ci y [y0-2, y0+17] = 20 rows; eta y [y0-1, y0+16] = 18 rows.
#define RCH 18
#define RST 72
// dF tiles: interior only, 16 chunks x 16 rows, dense stride 64.
#define SST 64
// LDS: 5760*2 + 5184 + 4096*2 = 24896 B -> 6 blocks/CU.

typedef float f4 __attribute__((ext_vector_type(4)));

__device__ __forceinline__ float scal(const float* __restrict__ p) {
    return fabsf(p[0]) + 0.001f;
}
__device__ __forceinline__ float clip01(float v) {
    return fminf(fmaxf(v, 0.0f), 1.0f);
}
// log2 of clamped arg; caller folds ln2 into the kBT scalar (kl).
__device__ __forceinline__ float lg2m(float m) {
    return __log2f(fmaxf(m, EPS));   // jnp.log(where(m<eps,eps,m)) == ln2*log2(max(m,eps))
}

__global__ __launch_bounds__(256, 6) void irr_fused(
    const float* __restrict__ cv,
    const float* __restrict__ ci,
    const float* __restrict__ eta,
    const float* __restrict__ p_ev,
    const float* __restrict__ p_ei,
    const float* __restrict__ p_kbt,
    const float* __restrict__ p_kv,
    const float* __restrict__ p_ki,
    const float* __restrict__ p_ke,
    const float* __restrict__ p_dv,
    const float* __restrict__ p_di,
    const float* __restrict__ p_L,
    float* __restrict__ cv_new,
    float* __restrict__ ci_new,
    float* __restrict__ eta_new)
{
    __shared__ __attribute__((aligned(16))) float scv[20][RST];
    __shared__ __attribute__((aligned(16))) float sci[20][RST];
    __shared__ __attribute__((aligned(16))) float seta[18][RST];
    __shared__ __attribute__((aligned(16))) float sdv[16][SST];
    __shared__ __attribute__((aligned(16))) float sdi[16][SST];

    const int tid = threadIdx.x;
    const int x0 = blockIdx.x * TX;
    const int y0 = blockIdx.y * TY;
    const int bbase = blockIdx.z * HW;

    const float energy_v = scal(p_ev);
    const float energy_i = scal(p_ei);
    const float kBT      = scal(p_kbt);
    const float kappa_v  = scal(p_kv);
    const float kappa_i  = scal(p_ki);
    const float kappa_e  = scal(p_ke);
    const float diff_v   = scal(p_dv);
    const float diff_i   = scal(p_di);
    const float L        = scal(p_L);
    const float kl   = kBT * 0.69314718056f;   // kBT*ln2: folds log2->ln
    const float dtl  = DT * L;
    const float dtrv = DT * diff_v / kBT;      // DT * mv / cv
    const float dtri = DT * diff_i / kBT;

    // ---- Stage raw fields into LDS with float4 coalesced loads ----
    // cv: 360 chunks, ci: 360, eta: 324 -> 1044 tasks (4 full passes + 20).
    for (int t = tid; t < 1044; t += 256) {
        const float* __restrict__ src;
        float (*dstA)[RST];
        int r, gy0;
        if (t < 360)      { src = cv;  r = t;       gy0 = y0 - 2; dstA = scv; }
        else if (t < 720) { src = ci;  r = t - 360; gy0 = y0 - 2; dstA = sci; }
        else              { src = eta; r = t - 720; gy0 = y0 - 1; dstA = seta; }
        const int cx = r % RCH;
        const int cy = r / RCH;
        const int gx = (x0 - 4 + (cx << 2)) & WMASK;   // 4-aligned, no row-cross
        const int gy = (gy0 + cy) & WMASK;
        const f4 v = *(const f4*)(src + bbase + (gy << LOG2W) + gx);
        *(f4*)&dstA[cy][cx << 2] = v;
    }
    __syncthreads();

    // ---- Phase 1: straight-line, 1 interior chunk per thread. ----
    // Quarter-wave groups (lanes 0-15) read dense 256B row segments: no
    // bank conflicts on any b128 below by construction.
    const int k  = tid & 15;          // chunk col; global x = x0 + 4k
    const int ey = tid >> 4;          // row;       global y = y0 + ey
    const int rx = (k << 2) + 4;      // raw float col of x0+4k

    const f4    cC = *(const f4*)&scv[ey + 2][rx];
    const f4    cU = *(const f4*)&scv[ey + 1][rx];
    const f4    cD = *(const f4*)&scv[ey + 3][rx];
    const float cL = scv[ey + 2][rx - 1];
    const float cR = scv[ey + 2][rx + 4];

    const f4    iC = *(const f4*)&sci[ey + 2][rx];
    const f4    iU = *(const f4*)&sci[ey + 1][rx];
    const f4    iD = *(const f4*)&sci[ey + 3][rx];
    const float iL = sci[ey + 2][rx - 1];
    const float iR = sci[ey + 2][rx + 4];

    const f4    eC = *(const f4*)&seta[ey + 1][rx];
    const f4    eU = *(const f4*)&seta[ey][rx];
    const f4    eD = *(const f4*)&seta[ey + 2][rx];
    const float eL = seta[ey + 1][rx - 1];
    const float eR = seta[ey + 1][rx + 4];

    f4 dv, di, en;
    #pragma unroll
    for (int j = 0; j < 4; ++j) {
        const float c0 = cC[j];
        const float i0 = iC[j];
        const float e0 = eC[j];
        const float cl = (j == 0) ? cL : cC[j - 1];
        const float cr = (j == 3) ? cR : cC[j + 1];
        const float il = (j == 0) ? iL : iC[j - 1];
        const float ir = (j == 3) ? iR : iC[j + 1];
        const float el = (j == 0) ? eL : eC[j - 1];
        const float er = (j == 3) ? eR : eC[j + 1];

        const float lap_cv  = cl + cr + cU[j] + cD[j] - 4.0f * c0;
        const float lap_ci  = il + ir + iU[j] + iD[j] - 4.0f * i0;
        const float lap_eta = el + er + eU[j] + eD[j] - 4.0f * e0;

        const float h  = (e0 - 1.0f) * (e0 - 1.0f);
        const float jj = e0 * e0;
        const float cs = 1.0f - c0 - i0;
        const float lgv = lg2m(c0);
        const float lgi = lg2m(i0);
        const float lgs = lg2m(cs);

        dv[j] = h * (energy_v + kl * (lgv - lgs)) + jj * (2.0f * (c0 - 1.0f))
              - kappa_v * lap_cv;
        di[j] = h * (energy_i + kl * (lgi - lgs)) + jj * (2.0f * i0)
              - kappa_i * lap_ci;

        const float fs = energy_v * c0 + energy_i * i0
                       + kl * (c0 * lgv + i0 * lgi + cs * lgs);
        const float fv = (c0 - 1.0f) * (c0 - 1.0f) + i0 * i0;
        const float dF_deta = fs * 2.0f * (e0 - 1.0f) + fv * 2.0f * e0
                            - kappa_e * lap_eta;   // N_PARAM == 1.0
        en[j] = clip01(fmaf(-dtl, dF_deta, e0));
    }

    const int c = k << 2;
    *(f4*)&sdv[ey][c] = dv;
    *(f4*)&sdi[ey][c] = di;

    const int gidx = bbase + ((y0 + ey) << LOG2W) + (x0 + c);   // interior: no wrap
    __builtin_nontemporal_store(en, (f4*)(eta_new + gidx));

    __syncthreads();

    // ---- Phase 2: centers from registers (vC==dv, c0==cC); halo dF from
    //      dense LDS, except tile-edge halo which is recomputed locally. ----
    auto evalpt = [&](int cr, int cc, int er) -> float2 {
        // dF_dcv/dF_dci at raw col cc, cv/ci row cr, eta row er
        const float c0 = scv[cr][cc];
        const float lap_cv = scv[cr][cc - 1] + scv[cr][cc + 1]
                           + scv[cr - 1][cc] + scv[cr + 1][cc] - 4.0f * c0;
        const float i0 = sci[cr][cc];
        const float lap_ci = sci[cr][cc - 1] + sci[cr][cc + 1]
                           + sci[cr - 1][cc] + sci[cr + 1][cc] - 4.0f * i0;
        const float e0 = seta[er][cc];
        const float h  = (e0 - 1.0f) * (e0 - 1.0f);
        const float jj = e0 * e0;
        const float cs = 1.0f - c0 - i0;
        const float lgv = lg2m(c0);
        const float lgi = lg2m(i0);
        const float lgs = lg2m(cs);
        const float dvx = h * (energy_v + kl * (lgv - lgs))
                        + jj * (2.0f * (c0 - 1.0f)) - kappa_v * lap_cv;
        const float dix = h * (energy_i + kl * (lgi - lgs))
                        + jj * (2.0f * i0) - kappa_i * lap_ci;
        return make_float2(dvx, dix);
    };

    float vL, wL, vR, wR;
    if (k == 0) {
        const float2 r = evalpt(ey + 2, 3, ey + 1);      // dF(x0-1, y0+ey)
        vL = r.x; wL = r.y;
    } else {
        vL = sdv[ey][c - 1]; wL = sdi[ey][c - 1];
    }
    if (k == 15) {
        const float2 r = evalpt(ey + 2, 68, ey + 1);     // dF(x0+64, y0+ey)
        vR = r.x; wR = r.y;
    } else {
        vR = sdv[ey][c + 4]; wR = sdi[ey][c + 4];
    }

    f4 vU, wU, vD, wD;
    if (ey == 0) {
        #pragma unroll
        for (int j = 0; j < 4; ++j) {                    // dF(y0-1, x0+4k+j)
            const float2 r = evalpt(1, rx + j, 0);
            vU[j] = r.x; wU[j] = r.y;
        }
    } else {
        vU = *(const f4*)&sdv[ey - 1][c];
        wU = *(const f4*)&sdi[ey - 1][c];
    }
    if (ey == 15) {
        #pragma unroll
        for (int j = 0; j < 4; ++j) {                    // dF(y0+16, x0+4k+j)
            const float2 r = evalpt(18, rx + j, 17);
            vD[j] = r.x; wD[j] = r.y;
        }
    } else {
        vD = *(const f4*)&sdv[ey + 1][c];
        wD = *(const f4*)&sdi[ey + 1][c];
    }

    f4 outv, outi;
    #pragma unroll
    for (int j = 0; j < 4; ++j) {
        const float lv = ((j == 0) ? vL : dv[j - 1]) + ((j == 3) ? vR : dv[j + 1])
                       + vU[j] + vD[j] - 4.0f * dv[j];
        const float li = ((j == 0) ? wL : di[j - 1]) + ((j == 3) ? wR : di[j + 1])
                       + wU[j] + wD[j] - 4.0f * di[j];
        outv[j] = clip01(fmaf(dtrv * cC[j], lv, cC[j]));
        outi[j] = clip01(fmaf(dtri * iC[j], li, iC[j]));
    }
    __builtin_nontemporal_store(outv, (f4*)(cv_new + gidx));
    __builtin_nontemporal_store(outi, (f4*)(ci_new + gidx));
}

extern "C" void kernel_launch(void* const* d_in, const int* in_sizes, int n_in,
                              void* d_out, int out_size, void* d_ws, size_t ws_size,
                              hipStream_t stream) {
    // Input order: cv, ci, eta, energy_v0, energy_i0, kBT0, kappa_v0, kappa_i0,
    //              kappa_eta0, diff_v0, diff_i0, L0  — all float32 per reference.
    const float* cv  = (const float*)d_in[0];
    const float* ci  = (const float*)d_in[1];
    const float* eta = (const float*)d_in[2];
    const float* p_ev  = (const float*)d_in[3];
    const float* p_ei  = (const float*)d_in[4];
    const float* p_kbt = (const float*)d_in[5];
    const float* p_kv  = (const float*)d_in[6];
    const float* p_ki  = (const float*)d_in[7];
    const float* p_ke  = (const float*)d_in[8];
    const float* p_dv  = (const float*)d_in[9];
    const float* p_di  = (const float*)d_in[10];
    const float* p_L   = (const float*)d_in[11];

    const int N = in_sizes[0];  // 8*1024*1024 elements

    float* out     = (float*)d_out;
    float* cv_new  = out;
    float* ci_new  = out + N;
    float* eta_new = out + 2 * N;

    const dim3 block(256);
    const dim3 grid(1024 / TX, 1024 / TY, N / HW);  // (16, 64, 8)

    irr_fused<<<grid, block, 0, stream>>>(cv, ci, eta, p_ev, p_ei, p_kbt,
                                          p_kv, p_ki, p_ke, p_dv, p_di, p_L,
                                          cv_new, ci_new, eta_new);
}